// Round 11
// baseline (5018.290 us; speedup 1.0000x reference)
//
#include <hip/hip_runtime.h>

#define NB 256      // batch
#define NT 512      // time steps
#define NH 1024     // hidden
#define BH (NB * NH)
#define GRID_WGS 256
#define BLOCK 512
#define T2 (2 * NT)

typedef __attribute__((ext_vector_type(8))) __bf16 bfrag;
typedef __attribute__((ext_vector_type(4))) float f32x4;
typedef __attribute__((ext_vector_type(4))) unsigned u32x4;
typedef __attribute__((ext_vector_type(2))) unsigned u32x2;
typedef __attribute__((ext_vector_type(8))) unsigned short u16x8;
typedef unsigned short us;

// h1(t) in buf[t&3]; h2(t) in buf[t&3] (quad buffers)
__device__ __attribute__((aligned(16))) us g_h1[4 * BH];
__device__ __attribute__((aligned(16))) us g_h2[4 * BH];
// independent monotonic flag arrays (never reset -> graph-replay safe)
__device__ __attribute__((aligned(128))) unsigned g_flagA[256];
__device__ __attribute__((aligned(128))) unsigned g_flagB[256];

__device__ __forceinline__ us f2bf(float f) {
  union { float f; unsigned u; } v; v.f = f;
  unsigned r = v.u + 0x7FFFu + ((v.u >> 16) & 1u);  // RTE
  return (us)(r >> 16);
}
__device__ __forceinline__ float bf2f(us u) {
  union { unsigned u; float f; } v; v.u = ((unsigned)u) << 16;
  return v.f;
}
__device__ __forceinline__ bfrag cvt8(const float* __restrict__ p) {
  f32x4 a = *reinterpret_cast<const f32x4*>(p);
  f32x4 b = *reinterpret_cast<const f32x4*>(p + 4);
  u16x8 u;
#pragma unroll
  for (int i = 0; i < 4; ++i) { u[i] = f2bf(a[i]); u[i + 4] = f2bf(b[i]); }
  union { u16x8 u; bfrag b; } c; c.u = u; return c.b;
}

// ---- device-coherent (sc0 sc1 -> L3 coherence point) ops
union f16u { u32x4 v; bfrag b; u16x8 s; };
__device__ __forceinline__ u32x4 ld16_dev(const void* p) {
  u32x4 r;
  asm volatile("global_load_dwordx4 %0, %1, off sc0 sc1" : "=v"(r) : "v"(p));
  return r;   // caller must s_waitcnt before use
}
__device__ __forceinline__ unsigned ld4_dev(const void* p) {
  unsigned r;
  asm volatile("global_load_dword %0, %1, off sc0 sc1\n\ts_waitcnt vmcnt(0)"
               : "=v"(r) : "v"(p) : "memory");
  return r;
}
__device__ __forceinline__ void st4_dev(void* p, unsigned v) {
  asm volatile("global_store_dword %0, %1, off sc0 sc1" :: "v"(p), "v"(v) : "memory");
}
__device__ __forceinline__ void st8_dev(void* p, unsigned lo, unsigned hi) {
  u32x2 v = {lo, hi};
  asm volatile("global_store_dwordx2 %0, %1, off sc0 sc1" :: "v"(p), "v"(v) : "memory");
}

// lanes 0..31 poll 32 flags until all >= tgt
__device__ __forceinline__ void poll32(const unsigned* f, int lane, unsigned tgt) {
  unsigned v = tgt;
  for (;;) {
    if (lane < 32) v = ld4_dev(f + lane);
    if (!__any((int)(v < tgt))) break;
    __builtin_amdgcn_s_sleep(1);
  }
}

// LDS counter ops (workgroup scope)
__device__ __forceinline__ unsigned cadd(unsigned* c) {
  return __hip_atomic_fetch_add(c, 1u, __ATOMIC_RELAXED, __HIP_MEMORY_SCOPE_WORKGROUP);
}
__device__ __forceinline__ void cwait(unsigned* c, unsigned tgt) {
  while (__hip_atomic_load(c, __ATOMIC_RELAXED, __HIP_MEMORY_SCOPE_WORKGROUP) < tgt) {}
}

#define MFMA(a, b, c) __builtin_amdgcn_mfma_f32_16x16x32_bf16((a), (b), (c), 0, 0, 0)
#define SB() __builtin_amdgcn_sched_barrier(0)
#define VM0() do { asm volatile("s_waitcnt vmcnt(0)" ::: "memory"); SB(); } while (0)
#define FENCE_REL() __builtin_amdgcn_fence(__ATOMIC_RELEASE, "workgroup")
#define FENCE_ACQ() __builtin_amdgcn_fence(__ATOMIC_ACQUIRE, "workgroup")

__global__ void __launch_bounds__(BLOCK, 2) rnn_kernel(
    const float* __restrict__ x,     // [B][2][T]
    const float* __restrict__ Wi1,   // [H][2]
    const float* __restrict__ Whh1,  // [H][H]
    const float* __restrict__ Wih2,  // [H][H]
    const float* __restrict__ Whh2,  // [H][H]
    const float* __restrict__ bih1,
    const float* __restrict__ bhh1,
    const float* __restrict__ bih2,
    const float* __restrict__ bhh2,
    const float* __restrict__ Wlin,  // [2][H]
    const float* __restrict__ blin,  // [2]
    float* __restrict__ out)         // [B][2][T]
{
  const int bid = blockIdx.x, tid = threadIdx.x;
  const int w = tid >> 6, lane = tid & 63;
  const int mb = bid >> 5, nb = bid & 31;   // group rows [mb*32,+32); cols [nb*32,+32)
  unsigned* fA = g_flagA + mb * 32;
  unsigned* fB = g_flagB + mb * 32;
  const unsigned fbA = ld4_dev(fA + nb);    // own flags -> stable bases
  const unsigned fbB = ld4_dev(fB + nb);

  __shared__ unsigned s_cnt[8];             // 0:cRed 1:cG2 2:cPubA 3:cG3 4:cPubB
  __shared__ float redA[4][32][36];
  __shared__ float redG2[2][4][32][36];
  __shared__ float redG3[4][32][36];
  unsigned* cRed  = &s_cnt[0]; unsigned* cG2   = &s_cnt[1];
  unsigned* cPubA = &s_cnt[2]; unsigned* cG3   = &s_cnt[3];
  unsigned* cPubB = &s_cnt[4];

  if (tid < 8) s_cnt[tid] = 0;

  // zero t=-1 tiles: h1(-1)=h1 buf3, h2(-1)=h2 buf3
  {
    const int zr = tid >> 4, zc = tid & 15;
    const int off_d = ((mb * 32 + zr) * NH + nb * 32) / 2 + zc;
    st4_dev((unsigned*)(g_h1 + 3 * BH) + off_d, 0u);
    st4_dev((unsigned*)(g_h2 + 3 * BH) + off_d, 0u);
  }

  const int fr = lane & 15;
  const int ko = (lane >> 4) << 3;          // 0,8,16,24
  const int prow = (lane >> 4) << 2;        // C/D row base in 16x16
  const int kh = w & 3;                     // K-quarter (A: w, B: w-4)
  const int kbase = kh * 256;
  const int erow = kh * 8 + (lane >> 3);    // epilogue local row 0..31
  const int ecol = (lane & 7) * 4;          // epilogue local col (x4)
  const int growE = mb * 32 + erow, gcolE = nb * 32 + ecol;
  const int arow = mb * 32 + fr;            // A-frag row base (+16 for mf1)

  VM0();
  __syncthreads();   // zeros acked + counters initialized, all 8 waves
  if (tid == 0) { st4_dev(fA + nb, fbA + 1u); st4_dev(fB + nb, fbB + 2u); }

  if (w < 4) {
    // ================= A-role: h1(q)=tanh(h1(q-1)W1^T + x Wi1^T + b1); G2 for B
    bfrag w1[2][8], w2i[2][8];
#pragma unroll
    for (int cf = 0; cf < 2; ++cf)
#pragma unroll
      for (int st = 0; st < 8; ++st) {
        const int off = (nb * 32 + cf * 16 + fr) * NH + kbase + st * 32 + ko;
        w1[cf][st]  = cvt8(Whh1 + off);
        w2i[cf][st] = cvt8(Wih2 + off);
      }
    const f32x4 b1 = *reinterpret_cast<const f32x4*>(bih1 + gcolE)
                   + *reinterpret_cast<const f32x4*>(bhh1 + gcolE);
    const f32x4 wa = *reinterpret_cast<const f32x4*>(Wi1 + gcolE * 2);
    const f32x4 wbv = *reinterpret_cast<const f32x4*>(Wi1 + gcolE * 2 + 4);
    f32x4 wi0, wi1;
    wi0[0]=wa[0]; wi0[1]=wa[2]; wi0[2]=wbv[0]; wi0[3]=wbv[2];
    wi1[0]=wa[1]; wi1[1]=wa[3]; wi1[2]=wbv[1]; wi1[3]=wbv[3];
    const float* xrow = x + growE * T2;

    for (int q = 0; q <= NT; ++q) {
      const bool last = (q == NT);
      const us* h1p = g_h1 + ((q + 3) & 3) * BH;   // h1(q-1)
      us*       h1c = g_h1 + (q & 3) * BH;          // h1(q)

      poll32(fA, lane, fbA + 1u + (unsigned)q); SB();

      f16u a[8];
      // ---- mf0
      {
        const us* pa = h1p + arow * NH + kbase + ko;
#pragma unroll
        for (int st = 0; st < 8; ++st) a[st].v = ld16_dev(pa + st * 32);
      }
      VM0();
      {
        f32x4 accW[2] = {}; f32x4 accG[2] = {};
#pragma unroll
        for (int st = 0; st < 8; ++st) {
          if (!last) {
            accW[0] = MFMA(a[st].b, w1[0][st], accW[0]);
            accW[1] = MFMA(a[st].b, w1[1][st], accW[1]);
          }
          accG[0] = MFMA(a[st].b, w2i[0][st], accG[0]);
          accG[1] = MFMA(a[st].b, w2i[1][st], accG[1]);
        }
        // gate redG2[q&1] recycling: B@(q-2) must be done
        if (lane == 0 && q >= 3) cwait(cPubB, 4u * (unsigned)(q - 2));
        FENCE_ACQ(); SB();
#pragma unroll
        for (int cf = 0; cf < 2; ++cf)
#pragma unroll
          for (int r = 0; r < 4; ++r) {
            redG2[q & 1][kh][prow + r][cf * 16 + fr] = accG[cf][r];
            if (!last) redA[kh][prow + r][cf * 16 + fr] = accW[cf][r];
          }
      }
      // ---- mf1
      {
        const us* pa = h1p + (arow + 16) * NH + kbase + ko;
#pragma unroll
        for (int st = 0; st < 8; ++st) a[st].v = ld16_dev(pa + st * 32);
      }
      VM0();
      {
        f32x4 accW[2] = {}; f32x4 accG[2] = {};
#pragma unroll
        for (int st = 0; st < 8; ++st) {
          if (!last) {
            accW[0] = MFMA(a[st].b, w1[0][st], accW[0]);
            accW[1] = MFMA(a[st].b, w1[1][st], accW[1]);
          }
          accG[0] = MFMA(a[st].b, w2i[0][st], accG[0]);
          accG[1] = MFMA(a[st].b, w2i[1][st], accG[1]);
        }
#pragma unroll
        for (int cf = 0; cf < 2; ++cf)
#pragma unroll
          for (int r = 0; r < 4; ++r) {
            redG2[q & 1][kh][16 + prow + r][cf * 16 + fr] = accG[cf][r];
            if (!last) redA[kh][16 + prow + r][cf * 16 + fr] = accW[cf][r];
          }
      }
      FENCE_REL();
      if (lane == 0) { cadd(cG2); if (!last) cadd(cRed); }

      if (!last) {
        const float x0 = xrow[q], x1 = xrow[NT + q];   // plain loads, post-VM0
        if (lane == 0) cwait(cRed, 4u * (unsigned)(q + 1));
        FENCE_ACQ(); SB();
        f32x4 s = {};
#pragma unroll
        for (int u = 0; u < 4; ++u)
          s += *reinterpret_cast<const f32x4*>(&redA[u][erow][ecol]);
        const f32x4 v = s + b1 + x0 * wi0 + x1 * wi1;
        st8_dev(h1c + growE * NH + gcolE,
                (unsigned)f2bf(tanhf(v[0])) | ((unsigned)f2bf(tanhf(v[1])) << 16),
                (unsigned)f2bf(tanhf(v[2])) | ((unsigned)f2bf(tanhf(v[3])) << 16));
        VM0();
        if (lane == 0) {
          const unsigned old = cadd(cPubA);
          if (old == 4u * (unsigned)q + 3u) st4_dev(fA + nb, fbA + 2u + (unsigned)q);
        }
      } else {
        if (w == 0 && lane == 0) st4_dev(fA + nb, fbA + 2u + (unsigned)NT);  // base sync
      }
    }

  } else {
    // ================= B-role: h2(p-1)=tanh(G2[from A] + h2(p-2)W2h^T + b2); out
    bfrag w2h[2][8];
#pragma unroll
    for (int cf = 0; cf < 2; ++cf)
#pragma unroll
      for (int st = 0; st < 8; ++st) {
        const int off = (nb * 32 + cf * 16 + fr) * NH + kbase + st * 32 + ko;
        w2h[cf][st] = cvt8(Whh2 + off);
      }
    const f32x4 b2 = *reinterpret_cast<const f32x4*>(bih2 + gcolE)
                   + *reinterpret_cast<const f32x4*>(bhh2 + gcolE);
    float wl[16];
    if (kh < 2) {
#pragma unroll
      for (int j = 0; j < 16; ++j) wl[j] = Wlin[kh * NH + lane * 16 + j];
    }
    const int r_g = mb * 32 + nb;

    for (int p = 1; p <= NT; ++p) {
      const us* h2p = g_h2 + ((p + 2) & 3) * BH;   // h2(p-2)
      us*       h2c = g_h2 + ((p + 3) & 3) * BH;   // h2(p-1)

      poll32(fB, lane, fbB + 1u + (unsigned)p); SB();

      f16u a[8], o0, o1;
      // ---- mf0
      {
        const us* pa = h2p + arow * NH + kbase + ko;
#pragma unroll
        for (int st = 0; st < 8; ++st) a[st].v = ld16_dev(pa + st * 32);
      }
      VM0();
      {
        f32x4 acc[2] = {};
#pragma unroll
        for (int st = 0; st < 8; ++st) {
          acc[0] = MFMA(a[st].b, w2h[0][st], acc[0]);
          acc[1] = MFMA(a[st].b, w2h[1][st], acc[1]);
        }
#pragma unroll
        for (int cf = 0; cf < 2; ++cf)
#pragma unroll
          for (int r = 0; r < 4; ++r)
            redG3[kh][prow + r][cf * 16 + fr] = acc[cf][r];
      }
      // ---- mf1 + out-row loads
      {
        const us* pa = h2p + (arow + 16) * NH + kbase + ko;
#pragma unroll
        for (int st = 0; st < 8; ++st) a[st].v = ld16_dev(pa + st * 32);
        o0.v = ld16_dev(h2p + r_g * NH + lane * 16);
        o1.v = ld16_dev(h2p + r_g * NH + lane * 16 + 8);
      }
      VM0();
      {
        f32x4 acc[2] = {};
#pragma unroll
        for (int st = 0; st < 8; ++st) {
          acc[0] = MFMA(a[st].b, w2h[0][st], acc[0]);
          acc[1] = MFMA(a[st].b, w2h[1][st], acc[1]);
        }
#pragma unroll
        for (int cf = 0; cf < 2; ++cf)
#pragma unroll
          for (int r = 0; r < 4; ++r)
            redG3[kh][16 + prow + r][cf * 16 + fr] = acc[cf][r];
      }
      FENCE_REL();
      if (lane == 0) {
        cadd(cG3);
        cwait(cG3, 4u * (unsigned)p);                 // all B partials
        cwait(cG2, 4u * (unsigned)(p + 1));           // A@p's G2 ready
      }
      FENCE_ACQ(); SB();

      f32x4 s = {};
#pragma unroll
      for (int u = 0; u < 4; ++u) {
        s += *reinterpret_cast<const f32x4*>(&redG3[u][erow][ecol]);
        s += *reinterpret_cast<const f32x4*>(&redG2[p & 1][u][erow][ecol]);
      }
      const f32x4 v = s + b2;
      st8_dev(h2c + growE * NH + gcolE,
              (unsigned)f2bf(tanhf(v[0])) | ((unsigned)f2bf(tanhf(v[1])) << 16),
              (unsigned)f2bf(tanhf(v[2])) | ((unsigned)f2bf(tanhf(v[3])) << 16));
      VM0();
      if (lane == 0) {
        const unsigned old = cadd(cPubB);
        if (old == 4u * (unsigned)p - 1u) st4_dev(fB + nb, fbB + 2u + (unsigned)p);
      }

      if (kh < 2 && p >= 2) {   // out(p-2), col = kh
        float so = 0.f;
#pragma unroll
        for (int e = 0; e < 8; ++e) {
          so = fmaf(bf2f(o0.s[e]), wl[e],     so);
          so = fmaf(bf2f(o1.s[e]), wl[8 + e], so);
        }
#pragma unroll
        for (int m = 1; m < 64; m <<= 1) so += __shfl_xor(so, m);
        if (lane == 0) out[r_g * T2 + kh * NT + (p - 2)] = so + blin[kh];
      }
    }

    // tail: out(NT-1)
    if (kh < 2) {
      poll32(fB, lane, fbB + 2u + (unsigned)NT); SB();
      const us* h2l = g_h2 + ((NT + 3) & 3) * BH;    // h2(NT-1)
      f16u o0, o1;
      o0.v = ld16_dev(h2l + r_g * NH + lane * 16);
      o1.v = ld16_dev(h2l + r_g * NH + lane * 16 + 8);
      VM0();
      float so = 0.f;
#pragma unroll
      for (int e = 0; e < 8; ++e) {
        so = fmaf(bf2f(o0.s[e]), wl[e],     so);
        so = fmaf(bf2f(o1.s[e]), wl[8 + e], so);
      }
#pragma unroll
      for (int m = 1; m < 64; m <<= 1) so += __shfl_xor(so, m);
      if (lane == 0) out[r_g * T2 + kh * NT + (NT - 1)] = so + blin[kh];
    }
  }
}

extern "C" void kernel_launch(void* const* d_in, const int* in_sizes, int n_in,
                              void* d_out, int out_size, void* d_ws, size_t ws_size,
                              hipStream_t stream) {
  (void)in_sizes; (void)n_in; (void)d_ws; (void)ws_size; (void)out_size;
  const float* x    = (const float*)d_in[0];
  const float* Wi1  = (const float*)d_in[1];
  const float* Whh1 = (const float*)d_in[2];
  const float* bih1 = (const float*)d_in[3];
  const float* bhh1 = (const float*)d_in[4];
  const float* Wih2 = (const float*)d_in[5];
  const float* Whh2 = (const float*)d_in[6];
  const float* bih2 = (const float*)d_in[7];
  const float* bhh2 = (const float*)d_in[8];
  const float* Wlin = (const float*)d_in[9];
  const float* blin = (const float*)d_in[10];
  float* out = (float*)d_out;

  void* args[] = { (void*)&x, (void*)&Wi1, (void*)&Whh1, (void*)&Wih2, (void*)&Whh2,
                   (void*)&bih1, (void*)&bhh1, (void*)&bih2, (void*)&bhh2,
                   (void*)&Wlin, (void*)&blin, (void*)&out };
  hipLaunchCooperativeKernel((void*)rnn_kernel, dim3(GRID_WGS), dim3(BLOCK),
                             args, 0, stream);
}